// Round 10
// baseline (2138.263 us; speedup 1.0000x reference)
//
#include <hip/hip_runtime.h>
#include <hip/hip_cooperative_groups.h>
#include <math.h>

namespace cg = cooperative_groups;

#define H 128
#define NGRAPH 64

using f32x4 = __attribute__((ext_vector_type(4))) float;
using f32x2 = __attribute__((ext_vector_type(2))) float;

__device__ inline float bf2f(ushort u) {
  unsigned int b = ((unsigned int)u) << 16;
  return __builtin_bit_cast(float, b);
}
__device__ inline ushort f2bf(float f) {
  unsigned int u = __builtin_bit_cast(unsigned int, f);
  u = (u + 0x7FFF + ((u >> 16) & 1)) >> 16;  // RNE
  return (ushort)u;
}

// accumulate 8 fp8 channels (uint2) scaled by n into acc[8]
#define ACC8(accv, v, n)                                                                     \
  {                                                                                          \
    f32x2 c;                                                                                 \
    c = __builtin_amdgcn_cvt_pk_f32_fp8((v).x, false);                                       \
    accv[0] = fmaf(n, c[0], accv[0]); accv[1] = fmaf(n, c[1], accv[1]);                      \
    c = __builtin_amdgcn_cvt_pk_f32_fp8((v).x, true);                                        \
    accv[2] = fmaf(n, c[0], accv[2]); accv[3] = fmaf(n, c[1], accv[3]);                      \
    c = __builtin_amdgcn_cvt_pk_f32_fp8((v).y, false);                                       \
    accv[4] = fmaf(n, c[0], accv[4]); accv[5] = fmaf(n, c[1], accv[5]);                      \
    c = __builtin_amdgcn_cvt_pk_f32_fp8((v).y, true);                                        \
    accv[6] = fmaf(n, c[0], accv[6]); accv[7] = fmaf(n, c[1], accv[7]);                      \
  }

// ================= cooperative build: init|cvt|count|scan|scatter|degnorm =================
__global__ __launch_bounds__(256, 2) void k_build(
    const float* __restrict__ x, unsigned char* __restrict__ x8,
    const float* __restrict__ w, unsigned char* __restrict__ w8,
    const int* __restrict__ row, const int* __restrict__ col,
    const float* __restrict__ ew,
    int* __restrict__ cnt, int* __restrict__ rank,
    int* __restrict__ bsum, int* __restrict__ boff, int* __restrict__ ptr,
    unsigned int* __restrict__ es, float* __restrict__ dis,
    float* __restrict__ pooled,
    int N, int E, int nb, int nx4, int nw4) {
  cg::grid_group gg = cg::this_grid();
  __shared__ int sh[256];
  int t = threadIdx.x;
  int gtid = blockIdx.x * 256 + t;
  int gsz = gridDim.x * 256;

  // phase 0: zero cnt + pooled (workspace is poisoned, not zeroed)
  for (int i = gtid; i < N; i += gsz) cnt[i] = 0;
  for (int i = gtid; i < NGRAPH * H; i += gsz) pooled[i] = 0.f;
  gg.sync();

  // phase 1: x fp32->fp8, weight transpose+cvt, per-node edge count (atomic rank)
  for (int i = gtid; i < nx4; i += gsz) {
    float4 v = *(const float4*)(x + (size_t)i * 4);
    int p = __builtin_amdgcn_cvt_pk_fp8_f32(v.x, v.y, 0, false);
    p = __builtin_amdgcn_cvt_pk_fp8_f32(v.z, v.w, p, true);
    *(unsigned int*)(x8 + (size_t)i * 4) = (unsigned int)p;
  }
  for (int i = gtid; i < nw4; i += gsz) {
    int f = i * 4;
    int l = f >> 16;
    int j = (f >> 9) & 127;
    int k = f & 511;  // k..k+3 within one q (4 | 128)
    int q = k >> 7, kk = k & 127;
    const float* src = w + (((size_t)(l * 4 + q) * H + kk) * H + j);
    float v0 = src[0], v1 = src[H], v2 = src[2 * H], v3 = src[3 * H];
    int p = __builtin_amdgcn_cvt_pk_fp8_f32(v0, v1, 0, false);
    p = __builtin_amdgcn_cvt_pk_fp8_f32(v2, v3, p, true);
    *(unsigned int*)(w8 + f) = (unsigned int)p;
  }
  for (int e = gtid; e < E; e += gsz) rank[e] = atomicAdd(&cnt[col[e]], 1);
  gg.sync();

  // phase 2: per-virtual-block reduction of cnt
  for (int vb = blockIdx.x; vb < nb; vb += gridDim.x) {
    int i = vb * 256 + t;
    int v = (i < N) ? cnt[i] : 0;
    sh[t] = v;
    __syncthreads();
    #pragma unroll
    for (int o = 128; o; o >>= 1) {
      if (t < o) sh[t] += sh[t + o];
      __syncthreads();
    }
    if (t == 0) bsum[vb] = sh[0];
    __syncthreads();
  }
  gg.sync();

  // phase 3: single-block exclusive scan of block sums (nb <= 256)
  if (blockIdx.x == 0) {
    int v = (t < nb) ? bsum[t] : 0;
    sh[t] = v;
    __syncthreads();
    #pragma unroll
    for (int d = 1; d < 256; d <<= 1) {
      int u = (t >= d) ? sh[t - d] : 0;
      __syncthreads();
      sh[t] += u;
      __syncthreads();
    }
    if (t < nb) boff[t] = sh[t] - v;
  }
  gg.sync();

  // phase 4: per-virtual-block exclusive scan + offset -> ptr
  for (int vb = blockIdx.x; vb < nb; vb += gridDim.x) {
    int i = vb * 256 + t;
    int v = (i < N) ? cnt[i] : 0;
    sh[t] = v;
    __syncthreads();
    #pragma unroll
    for (int d = 1; d < 256; d <<= 1) {
      int u = (t >= d) ? sh[t - d] : 0;
      __syncthreads();
      sh[t] += u;
      __syncthreads();
    }
    int ex = boff[vb] + sh[t] - v;
    if (i < N) {
      ptr[i] = ex;
      if (i == N - 1) ptr[N] = ex + v;
    }
    __syncthreads();
  }
  gg.sync();

  // phase 5: scatter packed (row:u16 | w:bf16) into CSC order — no atomics
  for (int e = gtid; e < E; e += gsz) {
    int pos = ptr[col[e]] + rank[e];
    es[pos] = ((unsigned int)row[e] & 0xFFFFu) | ((unsigned int)f2bf(ew[e]) << 16);
  }
  gg.sync();

  // phase 6: per-node degree -> dis = rsqrt(deg)
  for (int v = gtid; v < N; v += gsz) {
    int s = ptr[v], e = ptr[v + 1];
    float d = 0.f;
    for (int i = s; i < e; i++) d += bf2f((ushort)(es[i] >> 16));
    dis[v] = d > 0.f ? rsqrtf(d) : 0.f;
  }
  gg.sync();

  // phase 7: per-edge norm: es.hi = bf16(dis[row]*w*dis[col])
  for (int v = gtid; v < N; v += gsz) {
    int s = ptr[v], e = ptr[v + 1];
    float dv = dis[v];
    for (int i = s; i < e; i++) {
      unsigned int u = es[i];
      float nm = dis[u & 0xFFFFu] * bf2f((ushort)(u >> 16)) * dv;
      es[i] = (u & 0xFFFFu) | ((unsigned int)f2bf(nm) << 16);
    }
  }
}

// ================= cooperative 3-hop propagation =================
// one 16-lane group per dst node; lane owns 8 channels (8B) end-to-end;
// 4-deep gather pipeline; grid-stride over nodes; grid.sync between hops.
__device__ inline void prop_pass(const unsigned char* __restrict__ hin8,
                                 unsigned char* __restrict__ hout8,
                                 const int* __restrict__ ptr,
                                 const unsigned int* __restrict__ es, int N) {
  int stride = gridDim.x * 16;
  int l15 = threadIdx.x & 15;
  for (int node = blockIdx.x * 16 + (threadIdx.x >> 4); node < N; node += stride) {
    int s = ptr[node], e = ptr[node + 1];
    float a[8] = {0.f, 0.f, 0.f, 0.f, 0.f, 0.f, 0.f, 0.f};
    float bb[8] = {0.f, 0.f, 0.f, 0.f, 0.f, 0.f, 0.f, 0.f};
    const unsigned char* base = hin8 + l15 * 8;
    int i = s;
    for (; i + 3 < e; i += 4) {
      unsigned int u0 = es[i], u1 = es[i + 1], u2 = es[i + 2], u3 = es[i + 3];
      uint2 v0 = *(const uint2*)(base + (size_t)(u0 & 0xFFFFu) * H);
      uint2 v1 = *(const uint2*)(base + (size_t)(u1 & 0xFFFFu) * H);
      uint2 v2 = *(const uint2*)(base + (size_t)(u2 & 0xFFFFu) * H);
      uint2 v3 = *(const uint2*)(base + (size_t)(u3 & 0xFFFFu) * H);
      float n0 = bf2f((ushort)(u0 >> 16));
      float n1 = bf2f((ushort)(u1 >> 16));
      float n2 = bf2f((ushort)(u2 >> 16));
      float n3 = bf2f((ushort)(u3 >> 16));
      ACC8(a, v0, n0);
      ACC8(bb, v1, n1);
      ACC8(a, v2, n2);
      ACC8(bb, v3, n3);
    }
    for (; i < e; i++) {
      unsigned int u0 = es[i];
      uint2 v0 = *(const uint2*)(base + (size_t)(u0 & 0xFFFFu) * H);
      float n0 = bf2f((ushort)(u0 >> 16));
      ACC8(a, v0, n0);
    }
    #pragma unroll
    for (int j = 0; j < 8; j++) a[j] += bb[j];
    int p0 = __builtin_amdgcn_cvt_pk_fp8_f32(a[0], a[1], 0, false);
    p0 = __builtin_amdgcn_cvt_pk_fp8_f32(a[2], a[3], p0, true);
    int p1 = __builtin_amdgcn_cvt_pk_fp8_f32(a[4], a[5], 0, false);
    p1 = __builtin_amdgcn_cvt_pk_fp8_f32(a[6], a[7], p1, true);
    *(uint2*)(hout8 + (size_t)node * H + l15 * 8) =
        make_uint2((unsigned int)p0, (unsigned int)p1);
  }
}

// (256,4): min 4 waves/EU -> VGPR cap 128 (no spill for this ~60-VGPR body);
// grid 1024 = 4 blocks/CU exactly -> cooperative co-residency validated.
__global__ __launch_bounds__(256, 4) void k_prop3(const unsigned char* __restrict__ X,
                                                  unsigned char* __restrict__ B0,
                                                  unsigned char* __restrict__ B1,
                                                  unsigned char* __restrict__ B2,
                                                  const int* __restrict__ ptr,
                                                  const unsigned int* __restrict__ es, int N) {
  cg::grid_group gg = cg::this_grid();
  prop_pass(X, B0, ptr, es, N);
  gg.sync();
  prop_pass(B0, B1, ptr, es, N);
  gg.sync();
  prop_pass(B1, B2, ptr, es, N);
}

// ================= fused TAGConv GEMM (fp8 MFMA): O8 = relu([X0|X1|X2|X3] @ Wcat + b) ====
__global__ __launch_bounds__(256) void k_fgemm(const unsigned char* __restrict__ X0,
                                               const unsigned char* __restrict__ X1,
                                               const unsigned char* __restrict__ X2,
                                               const unsigned char* __restrict__ X3,
                                               const unsigned char* __restrict__ W8,  // [128][512] fp8 (j-major)
                                               const float* __restrict__ bias,
                                               unsigned char* __restrict__ O8, int N) {
  __shared__ unsigned char As[128][72];
  __shared__ unsigned char Bs[128][72];
  int t = threadIdx.x;
  int r0 = blockIdx.x * 128;
  int w = t >> 6, lane = t & 63;
  int mw = w >> 1, nw = w & 1;
  int l15 = lane & 15, l4 = lane >> 4;

  f32x4 acc[4][4];
  #pragma unroll
  for (int i = 0; i < 4; i++)
    #pragma unroll
    for (int j = 0; j < 4; j++) acc[i][j] = (f32x4){0.f, 0.f, 0.f, 0.f};

  for (int it = 0; it < 8; ++it) {
    const unsigned char* Xp = (it < 2) ? X0 : (it < 4) ? X1 : (it < 6) ? X2 : X3;
    int kb = (it & 1) * 64;
    int k0 = it * 64;
    #pragma unroll
    for (int p = 0; p < 2; p++) {
      int idx = t + p * 256;          // 0..511
      int rj = idx >> 2;              // 0..127
      int kc = (idx & 3) << 4;        // 0,16,32,48
      int gr = r0 + rj;
      uint4 av = make_uint4(0, 0, 0, 0);
      if (gr < N) av = *(const uint4*)(Xp + (size_t)gr * H + kb + kc);
      *(uint4*)&As[rj][kc] = av;
      *(uint4*)&Bs[rj][kc] = *(const uint4*)(W8 + (size_t)rj * 512 + k0 + kc);
    }
    __syncthreads();
    #pragma unroll
    for (int ks = 0; ks < 2; ks++) {
      int kk = ks * 32 + l4 * 8;
      long a[4], b[4];
      #pragma unroll
      for (int mf = 0; mf < 4; mf++) a[mf] = *(const long*)&As[mw * 64 + mf * 16 + l15][kk];
      #pragma unroll
      for (int nf = 0; nf < 4; nf++) b[nf] = *(const long*)&Bs[nw * 64 + nf * 16 + l15][kk];
      #pragma unroll
      for (int mf = 0; mf < 4; mf++)
        #pragma unroll
        for (int nf = 0; nf < 4; nf++)
          acc[mf][nf] = __builtin_amdgcn_mfma_f32_16x16x32_fp8_fp8(a[mf], b[nf], acc[mf][nf], 0, 0, 0);
    }
    __syncthreads();
  }

  #pragma unroll
  for (int nf = 0; nf < 4; nf++) {
    int colj = nw * 64 + nf * 16 + l15;
    float bv = bias[colj];
    #pragma unroll
    for (int mf = 0; mf < 4; mf++) {
      int rbase = r0 + mw * 64 + mf * 16 + l4 * 4;
      #pragma unroll
      for (int r = 0; r < 4; r++) {
        int rr = rbase + r;
        if (rr < N) {
          float v = fmaxf(acc[mf][nf][r] + bv, 0.f);
          O8[(size_t)rr * H + colj] =
              (unsigned char)(__builtin_amdgcn_cvt_pk_fp8_f32(v, v, 0, false) & 0xFF);
        }
      }
    }
  }
}

// ================= global mean pool (fp8 in): parallel atomic sums =================
#define POOL_ROWS 64
__global__ __launch_bounds__(256) void k_pool(const unsigned char* __restrict__ h8,
                                              const int* __restrict__ batch,
                                              float* __restrict__ pooled, int N) {
  int r0 = blockIdx.x * POOL_ROWS;
  int j2 = threadIdx.x & 63;   // channel pair: channels 2*j2, 2*j2+1
  int q = threadIdx.x >> 6;    // 0..3: row subset
  int rend = min(r0 + POOL_ROWS, N);
  float a0 = 0.f, a1 = 0.f;
  int cur = -1;
  for (int r = r0 + q; r < rend; r += 4) {
    int g = batch[r];
    if (g != cur) {
      if (cur >= 0) {
        atomicAdd(&pooled[cur * H + 2 * j2], a0);
        atomicAdd(&pooled[cur * H + 2 * j2 + 1], a1);
      }
      cur = g;
      a0 = a1 = 0.f;
    }
    unsigned int v = *(const ushort*)(h8 + (size_t)r * H + 2 * j2);
    f32x2 c = __builtin_amdgcn_cvt_pk_f32_fp8(v, false);
    a0 += c[0];
    a1 += c[1];
  }
  if (cur >= 0) {
    atomicAdd(&pooled[cur * H + 2 * j2], a0);
    atomicAdd(&pooled[cur * H + 2 * j2 + 1], a1);
  }
}

// ================= head: sigmoid((mean @ W1 + b1) @ W2 + b2), bounds inline =================
__global__ __launch_bounds__(128) void k_head(const float* __restrict__ pooled,
                                              const int* __restrict__ batch, int N,
                                              const float* __restrict__ w1,
                                              const float* __restrict__ b1,
                                              const float* __restrict__ w2,
                                              const float* __restrict__ b2,
                                              float* __restrict__ out) {
  int g = blockIdx.x;
  int j = threadIdx.x;
  __shared__ float pv[H];
  __shared__ float red[H];
  __shared__ int bnd[2];
  if (j < 2) {
    int target = g + j;
    int lo = 0, hi = N;
    while (lo < hi) {
      int mid = (lo + hi) >> 1;
      if (batch[mid] < target) lo = mid + 1;
      else hi = mid;
    }
    bnd[j] = lo;
  }
  __syncthreads();
  float c = (float)max(bnd[1] - bnd[0], 1);
  pv[j] = pooled[g * H + j] / c;
  __syncthreads();
  float t1 = b1[j];
  #pragma unroll 4
  for (int k = 0; k < H; k++) t1 = fmaf(pv[k], w1[k * H + j], t1);
  red[j] = t1 * w2[j];
  __syncthreads();
  if (j < 64) {
    float s = red[j] + red[j + 64];
    #pragma unroll
    for (int o = 32; o; o >>= 1) s += __shfl_down(s, o);
    if (j == 0) out[g] = 1.f / (1.f + expf(-(s + b2[0])));
  }
}

extern "C" void kernel_launch(void* const* d_in, const int* in_sizes, int n_in,
                              void* d_out, int out_size, void* d_ws, size_t ws_size,
                              hipStream_t stream) {
  const float* x = (const float*)d_in[0];
  const int* eidx = (const int*)d_in[1];
  const float* ew = (const float*)d_in[2];
  const int* batch = (const int*)d_in[3];
  const float* conv_ws = (const float*)d_in[4];  // [5][4][128][128]
  const float* conv_bs = (const float*)d_in[5];  // [5][128]
  const float* lin1_w = (const float*)d_in[6];
  const float* lin1_b = (const float*)d_in[7];
  const float* lin2_w = (const float*)d_in[8];
  const float* lin2_b = (const float*)d_in[9];
  float* out = (float*)d_out;

  int N = in_sizes[0] / H;  // 50000  (row packing assumes N <= 65535)
  int E = in_sizes[2];      // 800000
  const int* row = eidx;
  const int* col = eidx + E;

  char* p = (char*)d_ws;
  auto alloc = [&](size_t bytes) {
    char* q = p;
    p += (bytes + 255) & ~(size_t)255;
    return q;
  };
  int* cnt = (int*)alloc((size_t)N * 4);
  int* ptrb = (int*)alloc((size_t)(N + 1) * 4);
  int* rank = (int*)alloc((size_t)E * 4);
  float* dis = (float*)alloc((size_t)N * 4);
  unsigned int* es = (unsigned int*)alloc((size_t)E * 4);
  unsigned char* x8 = (unsigned char*)alloc((size_t)N * H);
  unsigned char* C0 = (unsigned char*)alloc((size_t)N * H);
  unsigned char* C1 = (unsigned char*)alloc((size_t)N * H);
  unsigned char* C2 = (unsigned char*)alloc((size_t)N * H);
  unsigned char* C3 = (unsigned char*)alloc((size_t)N * H);
  unsigned char* W8 = (unsigned char*)alloc((size_t)5 * H * 512);
  int* bsum = (int*)alloc(256 * 4);
  int* boff = (int*)alloc(256 * 4);
  float* pooled = (float*)alloc((size_t)NGRAPH * H * 4);

  int nx4 = N * H / 4;
  int nw4 = 5 * H * 512 / 4;
  int nb = (N + 255) / 256;  // 196 <= 256

  // ---- cooperative build (init + cvt + count + scan + scatter + degnorm) ----
  {
    void* args[] = {(void*)&x,    (void*)&x8,   (void*)&conv_ws, (void*)&W8,
                    (void*)&row,  (void*)&col,  (void*)&ew,      (void*)&cnt,
                    (void*)&rank, (void*)&bsum, (void*)&boff,    (void*)&ptrb,
                    (void*)&es,   (void*)&dis,  (void*)&pooled,  (void*)&N,
                    (void*)&E,    (void*)&nb,   (void*)&nx4,     (void*)&nw4};
    hipLaunchCooperativeKernel((void*)k_build, dim3(512), dim3(256), args, 0, stream);
  }

  int gemm_blocks = (N + 127) / 128;
  const unsigned char* P8 = x8;
  for (int layer = 0; layer < 5; layer++) {
    const unsigned char* Wl = W8 + (size_t)layer * H * 512;
    const float* bl = conv_bs + (size_t)layer * H;
    {
      void* args[] = {(void*)&P8, (void*)&C0, (void*)&C1,  (void*)&C2,
                      (void*)&ptrb, (void*)&es, (void*)&N};
      hipLaunchCooperativeKernel((void*)k_prop3, dim3(1024), dim3(256), args, 0, stream);
    }
    // O8=C3 aliases P8 for layers>=1: each fgemm block reads only its own 128
    // rows of X0 (staging) and writes those rows only in the epilogue -> safe.
    k_fgemm<<<gemm_blocks, 256, 0, stream>>>(P8, C0, C1, C2, Wl, bl, C3, N);
    P8 = C3;
  }

  k_pool<<<(N + POOL_ROWS - 1) / POOL_ROWS, 256, 0, stream>>>(P8, batch, pooled, N);
  k_head<<<NGRAPH, 128, 0, stream>>>(pooled, batch, N, lin1_w, lin1_b, lin2_w, lin2_b, out);
}

// Round 11
// 545.540 us; speedup vs baseline: 3.9195x; 3.9195x over previous
//
#include <hip/hip_runtime.h>
#include <math.h>

#define H 128
#define NGRAPH 64

using f32x4 = __attribute__((ext_vector_type(4))) float;
using f32x2 = __attribute__((ext_vector_type(2))) float;

__device__ inline float bf2f(ushort u) {
  unsigned int b = ((unsigned int)u) << 16;
  return __builtin_bit_cast(float, b);
}
__device__ inline ushort f2bf(float f) {
  unsigned int u = __builtin_bit_cast(unsigned int, f);
  u = (u + 0x7FFF + ((u >> 16) & 1)) >> 16;  // RNE
  return (ushort)u;
}

// accumulate 8 fp8 channels (uint2) scaled by n into acc[8]
#define ACC8(accv, v, n)                                                                     \
  {                                                                                          \
    f32x2 c;                                                                                 \
    c = __builtin_amdgcn_cvt_pk_f32_fp8((v).x, false);                                       \
    accv[0] = fmaf(n, c[0], accv[0]); accv[1] = fmaf(n, c[1], accv[1]);                      \
    c = __builtin_amdgcn_cvt_pk_f32_fp8((v).x, true);                                        \
    accv[2] = fmaf(n, c[0], accv[2]); accv[3] = fmaf(n, c[1], accv[3]);                      \
    c = __builtin_amdgcn_cvt_pk_f32_fp8((v).y, false);                                       \
    accv[4] = fmaf(n, c[0], accv[4]); accv[5] = fmaf(n, c[1], accv[5]);                      \
    c = __builtin_amdgcn_cvt_pk_f32_fp8((v).y, true);                                        \
    accv[6] = fmaf(n, c[0], accv[6]); accv[7] = fmaf(n, c[1], accv[7]);                      \
  }

// ---------------- merged setup: cvt_x | cvt_w | count (block-role ranges) ----------------
__global__ __launch_bounds__(256) void k_setup(const float* __restrict__ x,
                                               unsigned char* __restrict__ x8,
                                               const float* __restrict__ w,
                                               unsigned char* __restrict__ w8,
                                               const int* __restrict__ col,
                                               int* __restrict__ cnt, int* __restrict__ rank,
                                               int nx4, int nw4, int E, int bx, int bw) {
  int b = blockIdx.x;
  int t = threadIdx.x;
  if (b < bx) {  // x fp32 -> fp8 (interleaved [N][128] layout)
    int i = b * 256 + t;
    if (i < nx4) {
      float4 v = *(const float4*)(x + (size_t)i * 4);
      int p = __builtin_amdgcn_cvt_pk_fp8_f32(v.x, v.y, 0, false);
      p = __builtin_amdgcn_cvt_pk_fp8_f32(v.z, v.w, p, true);
      *(unsigned int*)(x8 + (size_t)i * 4) = (unsigned int)p;
    }
  } else if (b < bx + bw) {  // weights transpose+cvt: W8[l][j][k] = W[l][k/128][k%128][j]
    int i = (b - bx) * 256 + t;
    if (i < nw4) {
      int f = i * 4;
      int l = f >> 16;
      int j = (f >> 9) & 127;
      int k = f & 511;  // k..k+3 within one q (4 | 128)
      int q = k >> 7, kk = k & 127;
      const float* src = w + (((size_t)(l * 4 + q) * H + kk) * H + j);
      float v0 = src[0], v1 = src[H], v2 = src[2 * H], v3 = src[3 * H];
      int p = __builtin_amdgcn_cvt_pk_fp8_f32(v0, v1, 0, false);
      p = __builtin_amdgcn_cvt_pk_fp8_f32(v2, v3, p, true);
      *(unsigned int*)(w8 + f) = (unsigned int)p;
    }
  } else {  // count: rank[e] = old cnt[col[e]]++ (the ONLY atomic pass)
    int e = (b - bx - bw) * 256 + t;
    if (e < E) rank[e] = atomicAdd(&cnt[col[e]], 1);
  }
}

// ---------------- scan phase 1: per-block reduction of cnt ----------------
__global__ __launch_bounds__(256) void k_scan1(const int* __restrict__ cnt,
                                               int* __restrict__ bsum, int N) {
  int i = blockIdx.x * 256 + threadIdx.x;
  int v = (i < N) ? cnt[i] : 0;
  __shared__ int red[256];
  red[threadIdx.x] = v;
  __syncthreads();
  #pragma unroll
  for (int o = 128; o; o >>= 1) {
    if (threadIdx.x < o) red[threadIdx.x] += red[threadIdx.x + o];
    __syncthreads();
  }
  if (threadIdx.x == 0) bsum[blockIdx.x] = red[0];
}

// ---------------- scan phase 2: per-block (redundant bsum prefix) + local scan -> ptr ----
__global__ __launch_bounds__(256) void k_scan3(const int* __restrict__ cnt,
                                               const int* __restrict__ bsum,
                                               int* __restrict__ ptr, int N) {
  int vb = blockIdx.x;
  int t = threadIdx.x;
  __shared__ int sh[256];
  // block offset = sum of bsum[0..vb)
  int partial = 0;
  for (int j = t; j < vb; j += 256) partial += bsum[j];
  sh[t] = partial;
  __syncthreads();
  #pragma unroll
  for (int o = 128; o; o >>= 1) {
    if (t < o) sh[t] += sh[t + o];
    __syncthreads();
  }
  int boff = sh[0];
  __syncthreads();
  // local inclusive scan of this block's cnt chunk
  int i = vb * 256 + t;
  int v = (i < N) ? cnt[i] : 0;
  sh[t] = v;
  __syncthreads();
  #pragma unroll
  for (int d = 1; d < 256; d <<= 1) {
    int u = (t >= d) ? sh[t - d] : 0;
    __syncthreads();
    sh[t] += u;
    __syncthreads();
  }
  int ex = boff + sh[t] - v;
  if (i < N) {
    ptr[i] = ex;
    if (i == N - 1) ptr[N] = ex + v;
  }
}

// ---------------- scatter packed (row:u16 | w:bf16) into CSC order — NO atomics ----------
__global__ void k_scatter(const int* __restrict__ row, const int* __restrict__ col,
                          const float* __restrict__ w, const int* __restrict__ ptr,
                          const int* __restrict__ rank, unsigned int* __restrict__ es, int E) {
  int e = blockIdx.x * blockDim.x + threadIdx.x;
  if (e < E) {
    int pos = ptr[col[e]] + rank[e];
    es[pos] = ((unsigned int)row[e] & 0xFFFFu) | ((unsigned int)f2bf(w[e]) << 16);
  }
}

// ---------------- per-node degree -> dis = rsqrt(deg) ----------------
__global__ __launch_bounds__(256) void k_degnorm1(const int* __restrict__ ptr,
                                                  const unsigned int* __restrict__ es,
                                                  float* __restrict__ dis, int N) {
  int v = blockIdx.x * blockDim.x + threadIdx.x;
  if (v >= N) return;
  int s = ptr[v], e = ptr[v + 1];
  float d = 0.f;
  for (int i = s; i < e; i++) d += bf2f((ushort)(es[i] >> 16));
  dis[v] = d > 0.f ? rsqrtf(d) : 0.f;
}

// ---------------- per-edge norm: es.hi = bf16(dis[row]*w*dis[col]) ----------------
__global__ __launch_bounds__(256) void k_degnorm2(const int* __restrict__ ptr,
                                                  unsigned int* __restrict__ es,
                                                  const float* __restrict__ dis, int N) {
  int v = blockIdx.x * blockDim.x + threadIdx.x;
  if (v >= N) return;
  int s = ptr[v], e = ptr[v + 1];
  float dv = dis[v];
  for (int i = s; i < e; i++) {
    unsigned int u = es[i];
    float nm = dis[u & 0xFFFFu] * bf2f((ushort)(u >> 16)) * dv;
    es[i] = (u & 0xFFFFu) | ((unsigned int)f2bf(nm) << 16);
  }
}

// ---------------- propagation: fp8 gather, fp32 accumulate, fp8 write ----------------
// one 16-lane group per dst node (4 nodes/wave); lane owns 8 channels (8B);
// 8-deep gather pipeline; nontemporal edge-stream loads (protect L2 for h rows).
__global__ __launch_bounds__(256) void k_prop(const unsigned char* __restrict__ hin8,
                                              unsigned char* __restrict__ hout8,
                                              const int* __restrict__ ptr,
                                              const unsigned int* __restrict__ es, int N) {
  int node = (blockIdx.x * 256 + threadIdx.x) >> 4;
  if (node >= N) return;
  int l15 = threadIdx.x & 15;  // channel block: 8 fp8 at byte l15*8
  int s = ptr[node], e = ptr[node + 1];
  float a[8] = {0.f, 0.f, 0.f, 0.f, 0.f, 0.f, 0.f, 0.f};
  float b[8] = {0.f, 0.f, 0.f, 0.f, 0.f, 0.f, 0.f, 0.f};
  const unsigned char* base = hin8 + l15 * 8;
  int i = s;
  for (; i + 7 < e; i += 8) {
    unsigned int u[8];
    #pragma unroll
    for (int k = 0; k < 8; k++) u[k] = __builtin_nontemporal_load(&es[i + k]);
    uint2 v[8];
    #pragma unroll
    for (int k = 0; k < 8; k++) v[k] = *(const uint2*)(base + (size_t)(u[k] & 0xFFFFu) * H);
    #pragma unroll
    for (int k = 0; k < 8; k++) {
      float n = bf2f((ushort)(u[k] >> 16));
      if (k & 1) {
        ACC8(b, v[k], n);
      } else {
        ACC8(a, v[k], n);
      }
    }
  }
  for (; i + 1 < e; i += 2) {
    unsigned int u0 = __builtin_nontemporal_load(&es[i]);
    unsigned int u1 = __builtin_nontemporal_load(&es[i + 1]);
    uint2 v0 = *(const uint2*)(base + (size_t)(u0 & 0xFFFFu) * H);
    uint2 v1 = *(const uint2*)(base + (size_t)(u1 & 0xFFFFu) * H);
    float n0 = bf2f((ushort)(u0 >> 16));
    float n1 = bf2f((ushort)(u1 >> 16));
    ACC8(a, v0, n0);
    ACC8(b, v1, n1);
  }
  if (i < e) {
    unsigned int u0 = __builtin_nontemporal_load(&es[i]);
    uint2 v0 = *(const uint2*)(base + (size_t)(u0 & 0xFFFFu) * H);
    float n0 = bf2f((ushort)(u0 >> 16));
    ACC8(a, v0, n0);
  }
  #pragma unroll
  for (int j = 0; j < 8; j++) a[j] += b[j];
  int p0 = __builtin_amdgcn_cvt_pk_fp8_f32(a[0], a[1], 0, false);
  p0 = __builtin_amdgcn_cvt_pk_fp8_f32(a[2], a[3], p0, true);
  int p1 = __builtin_amdgcn_cvt_pk_fp8_f32(a[4], a[5], 0, false);
  p1 = __builtin_amdgcn_cvt_pk_fp8_f32(a[6], a[7], p1, true);
  *(uint2*)(hout8 + (size_t)node * H + l15 * 8) = make_uint2((unsigned int)p0, (unsigned int)p1);
}

// ---------------- fused TAGConv GEMM (fp8 MFMA): O = relu([X0|X1|X2|X3] @ Wcat + b) -----
// LAST=0: store fp8 O8.  LAST=1: reduce into per-graph pooled sums (no O8 store).
template <int LAST>
__global__ __launch_bounds__(256) void k_fgemm(const unsigned char* __restrict__ X0,
                                               const unsigned char* __restrict__ X1,
                                               const unsigned char* __restrict__ X2,
                                               const unsigned char* __restrict__ X3,
                                               const unsigned char* __restrict__ W8,  // [128][512] fp8 (j-major)
                                               const float* __restrict__ bias,
                                               unsigned char* __restrict__ O8,
                                               const int* __restrict__ batch,
                                               float* __restrict__ pooled, int N) {
  __shared__ unsigned char As[128][72];
  __shared__ unsigned char Bs[128][72];
  __shared__ float pl[4][H];   // per-graph partial sums (block spans <= 2 graphs; 4 safe)
  __shared__ int sb[128];      // batch id per block row
  int t = threadIdx.x;
  int r0 = blockIdx.x * 128;
  int w = t >> 6, lane = t & 63;
  int mw = w >> 1, nw = w & 1;
  int l15 = lane & 15, l4 = lane >> 4;

  if (LAST) {
    for (int k = t; k < 4 * H; k += 256) ((float*)pl)[k] = 0.f;
    if (t < 128 && r0 + t < N) sb[t] = batch[r0 + t];
  }

  f32x4 acc[4][4];
  #pragma unroll
  for (int i = 0; i < 4; i++)
    #pragma unroll
    for (int j = 0; j < 4; j++) acc[i][j] = (f32x4){0.f, 0.f, 0.f, 0.f};

  for (int it = 0; it < 8; ++it) {
    const unsigned char* Xp = (it < 2) ? X0 : (it < 4) ? X1 : (it < 6) ? X2 : X3;
    int kb = (it & 1) * 64;
    int k0 = it * 64;
    #pragma unroll
    for (int p = 0; p < 2; p++) {
      int idx = t + p * 256;          // 0..511
      int rj = idx >> 2;              // 0..127
      int kc = (idx & 3) << 4;        // 0,16,32,48
      int gr = r0 + rj;
      uint4 av = make_uint4(0, 0, 0, 0);
      if (gr < N) av = *(const uint4*)(Xp + (size_t)gr * H + kb + kc);
      *(uint4*)&As[rj][kc] = av;
      *(uint4*)&Bs[rj][kc] = *(const uint4*)(W8 + (size_t)rj * 512 + k0 + kc);
    }
    __syncthreads();
    #pragma unroll
    for (int ks = 0; ks < 2; ks++) {
      int kk = ks * 32 + l4 * 8;
      long a[4], b[4];
      #pragma unroll
      for (int mf = 0; mf < 4; mf++) a[mf] = *(const long*)&As[mw * 64 + mf * 16 + l15][kk];
      #pragma unroll
      for (int nf = 0; nf < 4; nf++) b[nf] = *(const long*)&Bs[nw * 64 + nf * 16 + l15][kk];
      #pragma unroll
      for (int mf = 0; mf < 4; mf++)
        #pragma unroll
        for (int nf = 0; nf < 4; nf++)
          acc[mf][nf] = __builtin_amdgcn_mfma_f32_16x16x32_fp8_fp8(a[mf], b[nf], acc[mf][nf], 0, 0, 0);
    }
    __syncthreads();
  }

  int g0 = 0;
  if (LAST) g0 = sb[0];

  #pragma unroll
  for (int nf = 0; nf < 4; nf++) {
    int colj = nw * 64 + nf * 16 + l15;
    float bv = bias[colj];
    #pragma unroll
    for (int mf = 0; mf < 4; mf++) {
      int rbase = mw * 64 + mf * 16 + l4 * 4;  // row within block
      #pragma unroll
      for (int r = 0; r < 4; r++) {
        int rr = r0 + rbase + r;
        if (rr < N) {
          float v = fmaxf(acc[mf][nf][r] + bv, 0.f);
          if (LAST) {
            int slot = sb[rbase + r] - g0;
            if (slot < 4) atomicAdd(&pl[slot][colj], v);
            else atomicAdd(&pooled[(size_t)sb[rbase + r] * H + colj], v);
          } else {
            O8[(size_t)rr * H + colj] =
                (unsigned char)(__builtin_amdgcn_cvt_pk_fp8_f32(v, v, 0, false) & 0xFF);
          }
        }
      }
    }
  }

  if (LAST) {
    __syncthreads();
    for (int k = t; k < 4 * H; k += 256) {
      int slot = k >> 7, colj = k & 127;
      float val = pl[slot][colj];
      if (val != 0.f && g0 + slot < NGRAPH)
        atomicAdd(&pooled[(size_t)(g0 + slot) * H + colj], val);
    }
  }
}

// ---------------- head: sigmoid((mean @ W1 + b1) @ W2 + b2), bounds inline ----------------
__global__ __launch_bounds__(128) void k_head(const float* __restrict__ pooled,
                                              const int* __restrict__ batch, int N,
                                              const float* __restrict__ w1,
                                              const float* __restrict__ b1,
                                              const float* __restrict__ w2,
                                              const float* __restrict__ b2,
                                              float* __restrict__ out) {
  int g = blockIdx.x;
  int j = threadIdx.x;
  __shared__ float pv[H];
  __shared__ float red[H];
  __shared__ int bnd[2];
  if (j < 2) {
    int target = g + j;
    int lo = 0, hi = N;
    while (lo < hi) {
      int mid = (lo + hi) >> 1;
      if (batch[mid] < target) lo = mid + 1;
      else hi = mid;
    }
    bnd[j] = lo;
  }
  __syncthreads();
  float c = (float)max(bnd[1] - bnd[0], 1);
  pv[j] = pooled[g * H + j] / c;
  __syncthreads();
  float t1 = b1[j];
  #pragma unroll 4
  for (int k = 0; k < H; k++) t1 = fmaf(pv[k], w1[k * H + j], t1);
  red[j] = t1 * w2[j];
  __syncthreads();
  if (j < 64) {
    float s = red[j] + red[j + 64];
    #pragma unroll
    for (int o = 32; o; o >>= 1) s += __shfl_down(s, o);
    if (j == 0) out[g] = 1.f / (1.f + expf(-(s + b2[0])));
  }
}

extern "C" void kernel_launch(void* const* d_in, const int* in_sizes, int n_in,
                              void* d_out, int out_size, void* d_ws, size_t ws_size,
                              hipStream_t stream) {
  const float* x = (const float*)d_in[0];
  const int* eidx = (const int*)d_in[1];
  const float* ew = (const float*)d_in[2];
  const int* batch = (const int*)d_in[3];
  const float* conv_ws = (const float*)d_in[4];  // [5][4][128][128]
  const float* conv_bs = (const float*)d_in[5];  // [5][128]
  const float* lin1_w = (const float*)d_in[6];
  const float* lin1_b = (const float*)d_in[7];
  const float* lin2_w = (const float*)d_in[8];
  const float* lin2_b = (const float*)d_in[9];
  float* out = (float*)d_out;

  const int N = in_sizes[0] / H;  // 50000  (row packing assumes N <= 65535)
  const int E = in_sizes[2];      // 800000
  const int* row = eidx;
  const int* col = eidx + E;

  char* p = (char*)d_ws;
  auto alloc = [&](size_t bytes) {
    char* q = p;
    p += (bytes + 255) & ~(size_t)255;
    return q;
  };
  int* cnt = (int*)alloc((size_t)N * 4);
  int* ptrb = (int*)alloc((size_t)(N + 1) * 4);
  int* rank = (int*)alloc((size_t)E * 4);
  float* dis = (float*)alloc((size_t)N * 4);
  unsigned int* es = (unsigned int*)alloc((size_t)E * 4);
  unsigned char* x8 = (unsigned char*)alloc((size_t)N * H);
  unsigned char* C0 = (unsigned char*)alloc((size_t)N * H);
  unsigned char* C1 = (unsigned char*)alloc((size_t)N * H);
  unsigned char* C2 = (unsigned char*)alloc((size_t)N * H);
  unsigned char* C3 = (unsigned char*)alloc((size_t)N * H);
  unsigned char* W8 = (unsigned char*)alloc((size_t)5 * H * 512);
  int* bsum = (int*)alloc(256 * 4);
  float* pooled = (float*)alloc((size_t)NGRAPH * H * 4);

  hipMemsetAsync(cnt, 0, (size_t)N * 4, stream);
  hipMemsetAsync(pooled, 0, (size_t)NGRAPH * H * 4, stream);

  int nx4 = N * H / 4;
  int nw4 = 5 * H * 512 / 4;
  int bx = (nx4 + 255) / 256;
  int bw = (nw4 + 255) / 256;
  int be = (E + 255) / 256;
  int nb = (N + 255) / 256;  // 196 <= 256

  k_setup<<<bx + bw + be, 256, 0, stream>>>(x, x8, conv_ws, W8, col, cnt, rank,
                                            nx4, nw4, E, bx, bw);
  k_scan1<<<nb, 256, 0, stream>>>(cnt, bsum, N);
  k_scan3<<<nb, 256, 0, stream>>>(cnt, bsum, ptrb, N);
  k_scatter<<<be, 256, 0, stream>>>(row, col, ew, ptrb, rank, es, E);
  k_degnorm1<<<nb, 256, 0, stream>>>(ptrb, es, dis, N);
  k_degnorm2<<<nb, 256, 0, stream>>>(ptrb, es, dis, N);

  int gemm_blocks = (N + 127) / 128;
  int prop_blocks = (N + 15) / 16;  // 16 nodes per 256-thread block (16 lanes/node)

  const unsigned char* P8 = x8;
  for (int layer = 0; layer < 5; layer++) {
    const unsigned char* Wl = W8 + (size_t)layer * H * 512;
    const float* bl = conv_bs + (size_t)layer * H;
    k_prop<<<prop_blocks, 256, 0, stream>>>(P8, C0, ptrb, es, N);
    k_prop<<<prop_blocks, 256, 0, stream>>>(C0, C1, ptrb, es, N);
    k_prop<<<prop_blocks, 256, 0, stream>>>(C1, C2, ptrb, es, N);
    // O8=C3 aliases P8 for layers>=1: each fgemm block reads only its own 128
    // rows of X0 (staging) and writes those rows only in the epilogue -> safe.
    if (layer < 4)
      k_fgemm<0><<<gemm_blocks, 256, 0, stream>>>(P8, C0, C1, C2, Wl, bl, C3, batch, pooled, N);
    else
      k_fgemm<1><<<gemm_blocks, 256, 0, stream>>>(P8, C0, C1, C2, Wl, bl, C3, batch, pooled, N);
    P8 = C3;
  }

  k_head<<<NGRAPH, 128, 0, stream>>>(pooled, batch, N, lin1_w, lin1_b, lin2_w, lin2_b, out);
}

// Round 12
// 482.337 us; speedup vs baseline: 4.4331x; 1.1310x over previous
//
#include <hip/hip_runtime.h>
#include <math.h>

#define H 128
#define NGRAPH 64

using f32x4 = __attribute__((ext_vector_type(4))) float;
using f32x2 = __attribute__((ext_vector_type(2))) float;

__device__ inline float bf2f(ushort u) {
  unsigned int b = ((unsigned int)u) << 16;
  return __builtin_bit_cast(float, b);
}
__device__ inline ushort f2bf(float f) {
  unsigned int u = __builtin_bit_cast(unsigned int, f);
  u = (u + 0x7FFF + ((u >> 16) & 1)) >> 16;  // RNE
  return (ushort)u;
}

// accumulate 8 fp8 channels (uint2) scaled by n into acc[8]
#define ACC8(accv, v, n)                                                                     \
  {                                                                                          \
    f32x2 c;                                                                                 \
    c = __builtin_amdgcn_cvt_pk_f32_fp8((v).x, false);                                       \
    accv[0] = fmaf(n, c[0], accv[0]); accv[1] = fmaf(n, c[1], accv[1]);                      \
    c = __builtin_amdgcn_cvt_pk_f32_fp8((v).x, true);                                        \
    accv[2] = fmaf(n, c[0], accv[2]); accv[3] = fmaf(n, c[1], accv[3]);                      \
    c = __builtin_amdgcn_cvt_pk_f32_fp8((v).y, false);                                       \
    accv[4] = fmaf(n, c[0], accv[4]); accv[5] = fmaf(n, c[1], accv[5]);                      \
    c = __builtin_amdgcn_cvt_pk_f32_fp8((v).y, true);                                        \
    accv[6] = fmaf(n, c[0], accv[6]); accv[7] = fmaf(n, c[1], accv[7]);                      \
  }

// ---------------- merged setup: cvt_x | cvt_w | count (block-role ranges) ----------------
__global__ __launch_bounds__(256) void k_setup(const float* __restrict__ x,
                                               unsigned char* __restrict__ x8,
                                               const float* __restrict__ w,
                                               unsigned char* __restrict__ w8,
                                               const int* __restrict__ col,
                                               int* __restrict__ cnt, int* __restrict__ rank,
                                               int nx4, int nw4, int E, int bx, int bw) {
  int b = blockIdx.x;
  int t = threadIdx.x;
  if (b < bx) {  // x fp32 -> fp8 (interleaved [N][128] layout)
    int i = b * 256 + t;
    if (i < nx4) {
      float4 v = *(const float4*)(x + (size_t)i * 4);
      int p = __builtin_amdgcn_cvt_pk_fp8_f32(v.x, v.y, 0, false);
      p = __builtin_amdgcn_cvt_pk_fp8_f32(v.z, v.w, p, true);
      *(unsigned int*)(x8 + (size_t)i * 4) = (unsigned int)p;
    }
  } else if (b < bx + bw) {  // weights transpose+cvt: W8[l][j][k] = W[l][k/128][k%128][j]
    int i = (b - bx) * 256 + t;
    if (i < nw4) {
      int f = i * 4;
      int l = f >> 16;
      int j = (f >> 9) & 127;
      int k = f & 511;  // k..k+3 within one q (4 | 128)
      int q = k >> 7, kk = k & 127;
      const float* src = w + (((size_t)(l * 4 + q) * H + kk) * H + j);
      float v0 = src[0], v1 = src[H], v2 = src[2 * H], v3 = src[3 * H];
      int p = __builtin_amdgcn_cvt_pk_fp8_f32(v0, v1, 0, false);
      p = __builtin_amdgcn_cvt_pk_fp8_f32(v2, v3, p, true);
      *(unsigned int*)(w8 + f) = (unsigned int)p;
    }
  } else {  // count: rank[e] = old cnt[col[e]]++ (the ONLY atomic pass)
    int e = (b - bx - bw) * 256 + t;
    if (e < E) rank[e] = atomicAdd(&cnt[col[e]], 1);
  }
}

// ---------------- scan phase 1: per-block reduction of cnt ----------------
__global__ __launch_bounds__(256) void k_scan1(const int* __restrict__ cnt,
                                               int* __restrict__ bsum, int N) {
  int i = blockIdx.x * 256 + threadIdx.x;
  int v = (i < N) ? cnt[i] : 0;
  __shared__ int red[256];
  red[threadIdx.x] = v;
  __syncthreads();
  #pragma unroll
  for (int o = 128; o; o >>= 1) {
    if (threadIdx.x < o) red[threadIdx.x] += red[threadIdx.x + o];
    __syncthreads();
  }
  if (threadIdx.x == 0) bsum[blockIdx.x] = red[0];
}

// ---------------- scan phase 2: per-block (redundant bsum prefix) + local scan -> ptr ----
__global__ __launch_bounds__(256) void k_scan3(const int* __restrict__ cnt,
                                               const int* __restrict__ bsum,
                                               int* __restrict__ ptr, int N) {
  int vb = blockIdx.x;
  int t = threadIdx.x;
  __shared__ int sh[256];
  int partial = 0;
  for (int j = t; j < vb; j += 256) partial += bsum[j];
  sh[t] = partial;
  __syncthreads();
  #pragma unroll
  for (int o = 128; o; o >>= 1) {
    if (t < o) sh[t] += sh[t + o];
    __syncthreads();
  }
  int boff = sh[0];
  __syncthreads();
  int i = vb * 256 + t;
  int v = (i < N) ? cnt[i] : 0;
  sh[t] = v;
  __syncthreads();
  #pragma unroll
  for (int d = 1; d < 256; d <<= 1) {
    int u = (t >= d) ? sh[t - d] : 0;
    __syncthreads();
    sh[t] += u;
    __syncthreads();
  }
  int ex = boff + sh[t] - v;
  if (i < N) {
    ptr[i] = ex;
    if (i == N - 1) ptr[N] = ex + v;
  }
}

// ---------------- scatter packed (row:u16 | w:bf16) into CSC order — NO atomics ----------
__global__ void k_scatter(const int* __restrict__ row, const int* __restrict__ col,
                          const float* __restrict__ w, const int* __restrict__ ptr,
                          const int* __restrict__ rank, unsigned int* __restrict__ es, int E) {
  int e = blockIdx.x * blockDim.x + threadIdx.x;
  if (e < E) {
    int pos = ptr[col[e]] + rank[e];
    es[pos] = ((unsigned int)row[e] & 0xFFFFu) | ((unsigned int)f2bf(w[e]) << 16);
  }
}

// ---------------- per-node degree -> dis = rsqrt(deg) ----------------
__global__ __launch_bounds__(256) void k_degnorm1(const int* __restrict__ ptr,
                                                  const unsigned int* __restrict__ es,
                                                  float* __restrict__ dis, int N) {
  int v = blockIdx.x * blockDim.x + threadIdx.x;
  if (v >= N) return;
  int s = ptr[v], e = ptr[v + 1];
  float d = 0.f;
  for (int i = s; i < e; i++) d += bf2f((ushort)(es[i] >> 16));
  dis[v] = d > 0.f ? rsqrtf(d) : 0.f;
}

// ---------------- per-edge norm: es.hi = bf16(dis[row]*w*dis[col]) ----------------
__global__ __launch_bounds__(256) void k_degnorm2(const int* __restrict__ ptr,
                                                  unsigned int* __restrict__ es,
                                                  const float* __restrict__ dis, int N) {
  int v = blockIdx.x * blockDim.x + threadIdx.x;
  if (v >= N) return;
  int s = ptr[v], e = ptr[v + 1];
  float dv = dis[v];
  for (int i = s; i < e; i++) {
    unsigned int u = es[i];
    float nm = dis[u & 0xFFFFu] * bf2f((ushort)(u >> 16)) * dv;
    es[i] = (u & 0xFFFFu) | ((unsigned int)f2bf(nm) << 16);
  }
}

// ---------------- propagation (R7-proven): fp8 gather, fp32 acc, fp8 write --------------
// one 16-lane group per dst node (4 nodes/wave); lane owns 8 channels (8B);
// 4-deep gather pipeline, dual accumulator banks.
__global__ __launch_bounds__(256) void k_prop(const unsigned char* __restrict__ hin8,
                                              unsigned char* __restrict__ hout8,
                                              const int* __restrict__ ptr,
                                              const unsigned int* __restrict__ es, int N) {
  int node = (blockIdx.x * 256 + threadIdx.x) >> 4;
  if (node >= N) return;
  int l15 = threadIdx.x & 15;  // channel block: 8 fp8 at byte l15*8
  int s = ptr[node], e = ptr[node + 1];
  float a[8] = {0.f, 0.f, 0.f, 0.f, 0.f, 0.f, 0.f, 0.f};
  float b[8] = {0.f, 0.f, 0.f, 0.f, 0.f, 0.f, 0.f, 0.f};
  const unsigned char* base = hin8 + l15 * 8;
  int i = s;
  for (; i + 3 < e; i += 4) {
    unsigned int u0 = es[i], u1 = es[i + 1], u2 = es[i + 2], u3 = es[i + 3];
    uint2 v0 = *(const uint2*)(base + (size_t)(u0 & 0xFFFFu) * H);
    uint2 v1 = *(const uint2*)(base + (size_t)(u1 & 0xFFFFu) * H);
    uint2 v2 = *(const uint2*)(base + (size_t)(u2 & 0xFFFFu) * H);
    uint2 v3 = *(const uint2*)(base + (size_t)(u3 & 0xFFFFu) * H);
    float n0 = bf2f((ushort)(u0 >> 16));
    float n1 = bf2f((ushort)(u1 >> 16));
    float n2 = bf2f((ushort)(u2 >> 16));
    float n3 = bf2f((ushort)(u3 >> 16));
    ACC8(a, v0, n0);
    ACC8(b, v1, n1);
    ACC8(a, v2, n2);
    ACC8(b, v3, n3);
  }
  for (; i < e; i++) {
    unsigned int u0 = es[i];
    uint2 v0 = *(const uint2*)(base + (size_t)(u0 & 0xFFFFu) * H);
    float n0 = bf2f((ushort)(u0 >> 16));
    ACC8(a, v0, n0);
  }
  #pragma unroll
  for (int j = 0; j < 8; j++) a[j] += b[j];
  int p0 = __builtin_amdgcn_cvt_pk_fp8_f32(a[0], a[1], 0, false);
  p0 = __builtin_amdgcn_cvt_pk_fp8_f32(a[2], a[3], p0, true);
  int p1 = __builtin_amdgcn_cvt_pk_fp8_f32(a[4], a[5], 0, false);
  p1 = __builtin_amdgcn_cvt_pk_fp8_f32(a[6], a[7], p1, true);
  *(uint2*)(hout8 + (size_t)node * H + l15 * 8) = make_uint2((unsigned int)p0, (unsigned int)p1);
}

// ---------------- fused TAGConv GEMM (fp8 MFMA), 64-row tiles, reg-prefetch pipeline ----
// O = relu([X0|X1|X2|X3] @ Wcat + b).  LAST=0: store fp8 O8. LAST=1: pooled sums.
// 4 waves; wave w owns rows w*16..w*16+15 x all 128 cols (acc[8] = 8x 16x16 frags).
template <int LAST>
__global__ __launch_bounds__(256) void k_fgemm(const unsigned char* __restrict__ X0,
                                               const unsigned char* __restrict__ X1,
                                               const unsigned char* __restrict__ X2,
                                               const unsigned char* __restrict__ X3,
                                               const unsigned char* __restrict__ W8,  // [128 j][512 k] fp8
                                               const float* __restrict__ bias,
                                               unsigned char* __restrict__ O8,
                                               const int* __restrict__ batch,
                                               float* __restrict__ pooled, int N) {
  __shared__ unsigned char As[64][72];    // [row][k] 64x64 chunk
  __shared__ unsigned char Bs[128][72];   // [col j][k] 128x64 chunk
  __shared__ float pl[4][H];
  __shared__ int sb[64];
  int t = threadIdx.x;
  int r0 = blockIdx.x * 64;
  int w = t >> 6, lane = t & 63;
  int l15 = lane & 15, l4 = lane >> 4;
  int rj = t >> 2, kc = (t & 3) << 4;  // staging coords: A row 0..63 / B rows rj, rj+64

  if (LAST) {
    for (int k = t; k < 4 * H; k += 256) ((float*)pl)[k] = 0.f;
    if (t < 64 && r0 + t < N) sb[t] = batch[r0 + t];
  }

  uint4 ra, rb0, rb1;
  auto issue = [&](int kt) {
    const unsigned char* Xp = (kt < 2) ? X0 : (kt < 4) ? X1 : (kt < 6) ? X2 : X3;
    int kb = (kt & 1) * 64;
    int gr = r0 + rj;
    ra = make_uint4(0, 0, 0, 0);
    if (gr < N) ra = *(const uint4*)(Xp + (size_t)gr * H + kb + kc);
    int k0 = kt * 64;
    rb0 = *(const uint4*)(W8 + (size_t)rj * 512 + k0 + kc);
    rb1 = *(const uint4*)(W8 + (size_t)(rj + 64) * 512 + k0 + kc);
  };

  f32x4 acc[8];
  #pragma unroll
  for (int i = 0; i < 8; i++) acc[i] = (f32x4){0.f, 0.f, 0.f, 0.f};

  issue(0);
  for (int kt = 0; kt < 8; ++kt) {
    *(uint4*)&As[rj][kc] = ra;
    *(uint4*)&Bs[rj][kc] = rb0;
    *(uint4*)&Bs[rj + 64][kc] = rb1;
    __syncthreads();
    if (kt < 7) issue(kt + 1);  // loads in flight while MFMA runs
    #pragma unroll
    for (int ks = 0; ks < 2; ks++) {
      int kk = ks * 32 + l4 * 8;
      long a = *(const long*)&As[w * 16 + l15][kk];
      #pragma unroll
      for (int nf = 0; nf < 8; nf++) {
        long b = *(const long*)&Bs[nf * 16 + l15][kk];
        acc[nf] = __builtin_amdgcn_mfma_f32_16x16x32_fp8_fp8(a, b, acc[nf], 0, 0, 0);
      }
    }
    __syncthreads();
  }

  int g0 = 0;
  if (LAST) g0 = sb[0];

  #pragma unroll
  for (int nf = 0; nf < 8; nf++) {
    int colj = nf * 16 + l15;
    float bv = bias[colj];
    #pragma unroll
    for (int r = 0; r < 4; r++) {
      int rblk = w * 16 + l4 * 4 + r;
      int rr = r0 + rblk;
      if (rr < N) {
        float v = fmaxf(acc[nf][r] + bv, 0.f);
        if (LAST) {
          int slot = sb[rblk] - g0;
          if (slot < 4) atomicAdd(&pl[slot][colj], v);
          else atomicAdd(&pooled[(size_t)sb[rblk] * H + colj], v);
        } else {
          O8[(size_t)rr * H + colj] =
              (unsigned char)(__builtin_amdgcn_cvt_pk_fp8_f32(v, v, 0, false) & 0xFF);
        }
      }
    }
  }

  if (LAST) {
    __syncthreads();
    for (int k = t; k < 4 * H; k += 256) {
      int slot = k >> 7, colj = k & 127;
      float val = pl[slot][colj];
      if (val != 0.f && g0 + slot < NGRAPH)
        atomicAdd(&pooled[(size_t)(g0 + slot) * H + colj], val);
    }
  }
}

// ---------------- head: sigmoid((mean @ W1 + b1) @ W2 + b2), bounds inline ----------------
__global__ __launch_bounds__(128) void k_head(const float* __restrict__ pooled,
                                              const int* __restrict__ batch, int N,
                                              const float* __restrict__ w1,
                                              const float* __restrict__ b1,
                                              const float* __restrict__ w2,
                                              const float* __restrict__ b2,
                                              float* __restrict__ out) {
  int g = blockIdx.x;
  int j = threadIdx.x;
  __shared__ float pv[H];
  __shared__ float red[H];
  __shared__ int bnd[2];
  if (j < 2) {
    int target = g + j;
    int lo = 0, hi = N;
    while (lo < hi) {
      int mid = (lo + hi) >> 1;
      if (batch[mid] < target) lo = mid + 1;
      else hi = mid;
    }
    bnd[j] = lo;
  }
  __syncthreads();
  float c = (float)max(bnd[1] - bnd[0], 1);
  pv[j] = pooled[g * H + j] / c;
  __syncthreads();
  float t1 = b1[j];
  #pragma unroll 4
  for (int k = 0; k < H; k++) t1 = fmaf(pv[k], w1[k * H + j], t1);
  red[j] = t1 * w2[j];
  __syncthreads();
  if (j < 64) {
    float s = red[j] + red[j + 64];
    #pragma unroll
    for (int o = 32; o; o >>= 1) s += __shfl_down(s, o);
    if (j == 0) out[g] = 1.f / (1.f + expf(-(s + b2[0])));
  }
}

extern "C" void kernel_launch(void* const* d_in, const int* in_sizes, int n_in,
                              void* d_out, int out_size, void* d_ws, size_t ws_size,
                              hipStream_t stream) {
  const float* x = (const float*)d_in[0];
  const int* eidx = (const int*)d_in[1];
  const float* ew = (const float*)d_in[2];
  const int* batch = (const int*)d_in[3];
  const float* conv_ws = (const float*)d_in[4];  // [5][4][128][128]
  const float* conv_bs = (const float*)d_in[5];  // [5][128]
  const float* lin1_w = (const float*)d_in[6];
  const float* lin1_b = (const float*)d_in[7];
  const float* lin2_w = (const float*)d_in[8];
  const float* lin2_b = (const float*)d_in[9];
  float* out = (float*)d_out;

  const int N = in_sizes[0] / H;  // 50000  (row packing assumes N <= 65535)
  const int E = in_sizes[2];      // 800000
  const int* row = eidx;
  const int* col = eidx + E;

  char* p = (char*)d_ws;
  auto alloc = [&](size_t bytes) {
    char* q = p;
    p += (bytes + 255) & ~(size_t)255;
    return q;
  };
  int* cnt = (int*)alloc((size_t)N * 4);
  int* ptrb = (int*)alloc((size_t)(N + 1) * 4);
  int* rank = (int*)alloc((size_t)E * 4);
  float* dis = (float*)alloc((size_t)N * 4);
  unsigned int* es = (unsigned int*)alloc((size_t)E * 4);
  unsigned char* x8 = (unsigned char*)alloc((size_t)N * H);
  unsigned char* C0 = (unsigned char*)alloc((size_t)N * H);
  unsigned char* C1 = (unsigned char*)alloc((size_t)N * H);
  unsigned char* C2 = (unsigned char*)alloc((size_t)N * H);
  unsigned char* C3 = (unsigned char*)alloc((size_t)N * H);
  unsigned char* W8 = (unsigned char*)alloc((size_t)5 * H * 512);
  int* bsum = (int*)alloc(256 * 4);
  float* pooled = (float*)alloc((size_t)NGRAPH * H * 4);

  hipMemsetAsync(cnt, 0, (size_t)N * 4, stream);
  hipMemsetAsync(pooled, 0, (size_t)NGRAPH * H * 4, stream);

  int nx4 = N * H / 4;
  int nw4 = 5 * H * 512 / 4;
  int bx = (nx4 + 255) / 256;
  int bw = (nw4 + 255) / 256;
  int be = (E + 255) / 256;
  int nb = (N + 255) / 256;  // 196 <= 256

  k_setup<<<bx + bw + be, 256, 0, stream>>>(x, x8, conv_ws, W8, col, cnt, rank,
                                            nx4, nw4, E, bx, bw);
  k_scan1<<<nb, 256, 0, stream>>>(cnt, bsum, N);
  k_scan3<<<nb, 256, 0, stream>>>(cnt, bsum, ptrb, N);
  k_scatter<<<be, 256, 0, stream>>>(row, col, ew, ptrb, rank, es, E);
  k_degnorm1<<<nb, 256, 0, stream>>>(ptrb, es, dis, N);
  k_degnorm2<<<nb, 256, 0, stream>>>(ptrb, es, dis, N);

  int gemm_blocks = (N + 63) / 64;      // 782 blocks -> ~3 blocks/CU
  int prop_blocks = (N + 15) / 16;      // 16 nodes per 256-thread block

  const unsigned char* P8 = x8;
  for (int layer = 0; layer < 5; layer++) {
    const unsigned char* Wl = W8 + (size_t)layer * H * 512;
    const float* bl = conv_bs + (size_t)layer * H;
    k_prop<<<prop_blocks, 256, 0, stream>>>(P8, C0, ptrb, es, N);
    k_prop<<<prop_blocks, 256, 0, stream>>>(C0, C1, ptrb, es, N);
    k_prop<<<prop_blocks, 256, 0, stream>>>(C1, C2, ptrb, es, N);
    // O8=C3 aliases P8 for layers>=1: each fgemm block reads only its own 64
    // rows of X0 (staging) and writes those rows only in the epilogue -> safe.
    if (layer < 4)
      k_fgemm<0><<<gemm_blocks, 256, 0, stream>>>(P8, C0, C1, C2, Wl, bl, C3, batch, pooled, N);
    else
      k_fgemm<1><<<gemm_blocks, 256, 0, stream>>>(P8, C0, C1, C2, Wl, bl, C3, batch, pooled, N);
    P8 = C3;
  }

  k_head<<<NGRAPH, 128, 0, stream>>>(pooled, batch, N, lin1_w, lin1_b, lin2_w, lin2_b, out);
}